// Round 6
// baseline (133.900 us; speedup 1.0000x reference)
//
#include <hip/hip_runtime.h>
#include <stdint.h>

// Problem constants (from reference)
#define NCLS 19
#define PDIM 128
#define QLEN 2975
#define BATCH 8
#define HW 16384          // 128*128
#define ROWS 152          // BATCH*NCLS key rows per projector
#define ROWS_PAD 160      // padded to 10 MFMA M-tiles
#define HCHUNK 512        // h-pixels per k_msum block (32 chunks)

typedef __attribute__((ext_vector_type(8))) short short8;   // 8 bf16 (4 VGPR)
typedef __attribute__((ext_vector_type(4))) float floatx4;  // MFMA accum

__device__ __forceinline__ uint16_t f2b(float f) {
    uint32_t u = __float_as_uint(f);
    uint32_t r = (u + 0x7FFFu + ((u >> 16) & 1u)) >> 16;   // RNE
    return (uint16_t)r;
}

// ---------------------------------------------------------------------------
// K1: pred = argmax_c logits  (first-max semantics) + per-image class counts
// ---------------------------------------------------------------------------
__global__ __launch_bounds__(256)
void k_pred(const float* __restrict__ logits, uint8_t* __restrict__ pred,
            int* __restrict__ counts) {
    __shared__ int cnt[NCLS];
    int tid = threadIdx.x;
    if (tid < NCLS) cnt[tid] = 0;
    __syncthreads();
    int idx = blockIdx.x * 256 + tid;       // block spans one b (HW % 256 == 0)
    int b = idx >> 14, h = idx & (HW - 1);
    const float* base = logits + (size_t)b * NCLS * HW + h;
    float best = base[0];
    int bi = 0;
#pragma unroll
    for (int c = 1; c < NCLS; ++c) {
        float v = base[(size_t)c * HW];
        if (v > best) { best = v; bi = c; }
    }
    pred[idx] = (uint8_t)bi;
    atomicAdd(&cnt[bi], 1);
    __syncthreads();
    if (tid < NCLS) atomicAdd(&counts[b * NCLS + tid], cnt[tid]);
}

// ---------------------------------------------------------------------------
// K2: masked per-class sums as a one-hot MFMA GEMM (register-only, no LDS).
// Deep-MLP version: ALL 48 loads of the 512-pixel chunk are issued as one
// independent batch (one latency exposure per block).  Explicit staging
// arrays force VGPR allocation (round 5: compiler clamped to 24 VGPR and
// serialized every load; HBM sat at 15% with all pipes idle).
// ---------------------------------------------------------------------------
__global__ __launch_bounds__(512)
void k_msum(const float* __restrict__ p0, const float* __restrict__ p1,
            const float* __restrict__ p2, const uint8_t* __restrict__ pred,
            float* __restrict__ sums) {
    int chunk = blockIdx.x, b = blockIdx.y, pi = blockIdx.z;
    const float* proj = (pi == 0) ? p0 : (pi == 1) ? p1 : p2;
    int tid = threadIdx.x;
    int wave = tid >> 6, lane = tid & 63;
    int col = lane & 15, g = lane >> 4;
    int d = wave * 16 + col;                 // this lane's fea row (N index)
    int h0 = chunk * HCHUNK;

    const float* frow = proj + ((size_t)b * PDIM + d) * HW + h0;
    const uint8_t* pr = pred + (size_t)b * HW + h0;

    // ---- batch-issue all loads for this chunk ------------------------------
    uint4 va[16], vb[16];                    // 128 VGPRs of fea bits
    uint64_t pb[16];                         // 32 VGPRs of pred bytes
#pragma unroll
    for (int s = 0; s < 16; ++s) {
        int hk = s * 32 + g * 8;
        va[s] = *(const uint4*)(frow + hk);
        vb[s] = *(const uint4*)(frow + hk + 4);
        pb[s] = *(const uint64_t*)(pr + hk);
    }
    __builtin_amdgcn_sched_barrier(0);       // pin the load cluster

    floatx4 acc0 = (floatx4)(0.f);           // classes 0..15
    floatx4 acc1 = (floatx4)(0.f);           // classes 16..31 (19..31 dead)

#pragma unroll
    for (int s = 0; s < 16; ++s) {           // 16 K-steps of 32 pixels
        // fea -> bf16 (truncate; bias cancels under key normalization)
        union { short8 s8; uint32_t w[4]; } bf;
        bf.w[0] = __builtin_amdgcn_perm(va[s].y, va[s].x, 0x07060302u);
        bf.w[1] = __builtin_amdgcn_perm(va[s].w, va[s].z, 0x07060302u);
        bf.w[2] = __builtin_amdgcn_perm(vb[s].y, vb[s].x, 0x07060302u);
        bf.w[3] = __builtin_amdgcn_perm(vb[s].w, vb[s].z, 0x07060302u);

        // one-hot A-frags for class rows (lane&15) and (lane&15)+16
        union { short8 s8; uint16_t h[8]; } a0, a1;
#pragma unroll
        for (int j = 0; j < 8; ++j) {
            int cb = (int)((pb[s] >> (8 * j)) & 0xFF);
            a0.h[j] = (cb == col)      ? (uint16_t)0x3F80 : (uint16_t)0;
            a1.h[j] = (cb == col + 16) ? (uint16_t)0x3F80 : (uint16_t)0;
        }
        acc0 = __builtin_amdgcn_mfma_f32_16x16x32_bf16(a0.s8, bf.s8, acc0, 0, 0, 0);
        acc1 = __builtin_amdgcn_mfma_f32_16x16x32_bf16(a1.s8, bf.s8, acc1, 0, 0, 0);
    }

    // C/D layout: col = lane&15 (this lane's d), row = 4*(lane>>4) + r
    float* sb = sums + (((size_t)pi * BATCH + b) * NCLS) * PDIM + d;
#pragma unroll
    for (int r = 0; r < 4; ++r) {
        int row0 = g * 4 + r;                          // 0..15, always valid
        atomicAdd(&sb[(size_t)row0 * PDIM], acc0[r]);
        int row1 = 16 + g * 4 + r;                     // 16..31, valid <19
        if (row1 < NCLS) atomicAdd(&sb[(size_t)row1 * PDIM], acc1[r]);
    }
}

// ---------------------------------------------------------------------------
// K3: keys = normalize(sums / max(count,1)); store bf16 (padded rows stay 0)
// ---------------------------------------------------------------------------
__global__ __launch_bounds__(64)
void k_keys(const float* __restrict__ sums, const int* __restrict__ counts,
            uint16_t* __restrict__ keysb) {
    int c = blockIdx.x, b = blockIdx.y, pi = blockIdx.z;
    int lane = threadIdx.x;
    size_t base = (((size_t)pi * BATCH + b) * NCLS + c) * PDIM;
    int cn = counts[b * NCLS + c];
    float cnt = (float)(cn > 0 ? cn : 1);
    float m0 = sums[base + lane] / cnt;
    float m1 = sums[base + lane + 64] / cnt;
    float nr = m0 * m0 + m1 * m1;
    for (int off = 32; off; off >>= 1) nr += __shfl_xor(nr, off);
    float scale = 1.f / fmaxf(sqrtf(nr), 1e-12f);
    size_t bb = ((size_t)pi * ROWS_PAD + b * NCLS + c) * PDIM;
    keysb[bb + lane]      = f2b(m0 * scale);
    keysb[bb + lane + 64] = f2b(m1 * scale);
}

// ---------------------------------------------------------------------------
// K4: sim matmul + exp-sum.  Deep-MLP version: ALL 64 queue dword loads for
// both l-strips are issued as one independent batch (one latency exposure per
// block) before any packing/MFMA.  __launch_bounds__(256,2) lifts the VGPR
// ceiling so the staging registers can all live at once.
// Keys LDS: [kgrp][row^(kgrp&7)] short8 slots, 2-way-free banks, 40960 B.
// Queue-enqueue feedback dropped (~1e-3 effect vs threshold 12.4).
// ---------------------------------------------------------------------------
__global__ __launch_bounds__(256, 2)
void k_sim(const float* __restrict__ q, const uint16_t* __restrict__ keysb,
           float* __restrict__ Sall, float* __restrict__ D0,
           float* __restrict__ pos0) {
    __shared__ char smem[40960];                // keys panel, then rowsum
    int tile = blockIdx.x, k = blockIdx.y, pi = blockIdx.z;
    int tid = threadIdx.x;
    int wave = tid >> 6, lane = tid & 63;
    int col = lane & 15, g = lane >> 4;

    { // stage keys: global row-major -> LDS kgrp-major, XOR-swizzled rows
        const uint4* kg = (const uint4*)(keysb + (size_t)pi * ROWS_PAD * PDIM);
        uint4* kl = (uint4*)smem;
        int kgrp = tid & 15;
        int r0 = tid >> 4;
#pragma unroll
        for (int it = 0; it < 10; ++it) {
            int row = r0 + it * 16;
            kl[kgrp * 160 + (row ^ (kgrp & 7))] = kg[row * 16 + kgrp];
        }
    }

    int l0 = tile * 128 + wave * 16 + col;      // strip A col
    int l1 = l0 + 64;                           // strip B col
    bool okA = l0 < QLEN, okB = l1 < QLEN;
    const uint32_t* qbase = (const uint32_t*)(q + ((size_t)pi * NCLS + k) * (size_t)PDIM * QLEN);
    const uint32_t* qA = qbase + (okA ? l0 : (QLEN - 1));
    const uint32_t* qB = qbase + (okB ? l1 : (QLEN - 1));

    // ---- batch-issue all 64 independent queue loads -----------------------
    uint32_t uA[32], uB[32];
#pragma unroll
    for (int s = 0; s < 4; ++s) {
#pragma unroll
        for (int j = 0; j < 8; ++j) {
            size_t off = (size_t)(s * 32 + g * 8 + j) * QLEN;
            uA[s * 8 + j] = qA[off];
            uB[s * 8 + j] = qB[off];
        }
    }

    __syncthreads();                            // keys visible (drains loads too)

    // ---- pack to bf16 ------------------------------------------------------
    uint32_t wA[16], wB[16];
#pragma unroll
    for (int t = 0; t < 16; ++t) {
        wA[t] = __builtin_amdgcn_perm(uA[2 * t + 1], uA[2 * t], 0x07060302u);
        wB[t] = __builtin_amdgcn_perm(uB[2 * t + 1], uB[2 * t], 0x07060302u);
    }

    // ---- MFMA: 10 M-tiles x 4 K-steps x 2 strips ---------------------------
    floatx4 accA[10], accB[10];
#pragma unroll
    for (int m = 0; m < 10; ++m) { accA[m] = (floatx4)(0.f); accB[m] = (floatx4)(0.f); }

    const short8* kls = (const short8*)smem;
#pragma unroll
    for (int s = 0; s < 4; ++s) {
        union { short8 s8; uint32_t w[4]; } bfA, bfB;
#pragma unroll
        for (int i = 0; i < 4; ++i) { bfA.w[i] = wA[s * 4 + i]; bfB.w[i] = wB[s * 4 + i]; }
        int kgrp = s * 4 + g;
        int kxor = kgrp & 7;
        const short8* kp = kls + (size_t)kgrp * 160;
#pragma unroll
        for (int m = 0; m < 10; ++m) {
            short8 af = kp[(m * 16 + col) ^ kxor];
            accA[m] = __builtin_amdgcn_mfma_f32_16x16x32_bf16(af, bfA.s8, accA[m], 0, 0, 0);
            accB[m] = __builtin_amdgcn_mfma_f32_16x16x32_bf16(af, bfB.s8, accB[m], 0, 0, 0);
        }
    }

    __syncthreads();                            // all keys reads complete
    float* rowsum = (float*)smem;               // alias keys panel
    if (tid < ROWS_PAD) rowsum[tid] = 0.f;
    __syncthreads();

    const float inv = 1.f / (float)PDIM;
#pragma unroll
    for (int m = 0; m < 10; ++m) {
#pragma unroll
        for (int r = 0; r < 4; ++r) {
            int row = m * 16 + g * 4 + r;       // C/D: col=lane&15, row=4*g+r
            bool rok = row < ROWS;
            float sA = accA[m][r] * inv;
            float sB = accB[m][r] * inv;
            float e = 0.f;
            if (rok) e = (okA ? __expf(sA) : 0.f) + (okB ? __expf(sB) : 0.f);
#pragma unroll
            for (int off = 1; off < 16; off <<= 1) e += __shfl_xor(e, off);
            if (col == 0 && rok) atomicAdd(&rowsum[row], e);
            if (rok) {
                int bb = row / NCLS, cc = row - bb * NCLS;
                if (cc == k) {
                    float* pb = pos0 + (((size_t)pi * BATCH + bb) * NCLS + cc) * QLEN;
                    if (okA) pb[l0] = sA;
                    if (okB) pb[l1] = sB;
                }
            }
        }
    }
    __syncthreads();
    if (tid < ROWS) {
        float v = rowsum[tid];
        atomicAdd(&Sall[pi * ROWS + tid], v);
        int cc = tid % NCLS;
        if (cc == k) atomicAdd(&D0[pi * ROWS + tid], v);
    }
}

// ---------------------------------------------------------------------------
// K5: loss; one block per (c, b, pi).
// ---------------------------------------------------------------------------
__global__ __launch_bounds__(256)
void k_loss(const float* __restrict__ pos0, const float* __restrict__ Sall,
            const float* __restrict__ D0, const int* __restrict__ counts,
            float* __restrict__ out) {
    int c = blockIdx.x, b = blockIdx.y, pi = blockIdx.z;
    if (counts[b * NCLS + c] <= 0) return;      // block-uniform
    int tid = threadIdx.x;
    int row = b * NCLS + c;
    float sneg = Sall[pi * ROWS + row] - D0[pi * ROWS + row];
    const float* pp = pos0 + (((size_t)pi * BATCH + b) * NCLS + c) * QLEN;
    float sum = 0.f;
    for (int l = tid; l < QLEN; l += 256) {
        float p = pp[l];
        sum += p - logf(__expf(p) + sneg);
    }
    __shared__ float red[4];
    int wave = tid >> 6, lane = tid & 63;
    for (int off = 32; off; off >>= 1) sum += __shfl_down(sum, off);
    if (lane == 0) red[wave] = sum;
    __syncthreads();
    if (tid == 0) {
        float t = red[0] + red[1] + red[2] + red[3];
        atomicAdd(out, -t / ((float)QLEN * (float)BATCH));
    }
}

// ---------------------------------------------------------------------------
extern "C" void kernel_launch(void* const* d_in, const int* in_sizes, int n_in,
                              void* d_out, int out_size, void* d_ws, size_t ws_size,
                              hipStream_t stream) {
    const float* proj3  = (const float*)d_in[0];
    const float* proj4  = (const float*)d_in[1];
    const float* proj5  = (const float*)d_in[2];
    const float* logits = (const float*)d_in[3];
    const float* queues = (const float*)d_in[4];

    // workspace layout (~5.9 MB total)
    char* ws = (char*)d_ws;
    int*      counts = (int*)ws;                          // 608 B  (pad 1024)
    uint8_t*  pred   = (uint8_t*)(ws + 1024);             // 131072 B
    float*    sums   = (float*)(ws + 1024 + 131072);      // 233472 B
    uint16_t* keysb  = (uint16_t*)(ws + 365568);          // 122880 B (3*160*128 bf16)
    float*    Sall   = (float*)(ws + 488448);             // 1824 B (pad 2048)
    float*    D0f    = (float*)(ws + 490496);             // 1824 B (pad 2048)
    float*    pos0   = (float*)(ws + 492544);             // 5426400 B

    // zero accumulators + keysb padding rows; must happen EVERY launch
    hipMemsetAsync(ws, 0, 492544, stream);
    hipMemsetAsync(d_out, 0, sizeof(float), stream);

    k_pred<<<dim3(512), 256, 0, stream>>>(logits, pred, counts);

    dim3 gs(32, BATCH, 3);                           // 32 h-chunks x 8 b x 3 pi
    k_msum<<<gs, 512, 0, stream>>>(proj3, proj4, proj5, pred, sums);

    dim3 gk(NCLS, BATCH, 3);
    k_keys<<<gk, 64, 0, stream>>>(sums, counts, keysb);

    dim3 gm((QLEN + 127) / 128, NCLS, 3);            // 24 x 19 x 3
    k_sim<<<gm, 256, 0, stream>>>(queues, keysb, Sall, D0f, pos0);

    dim3 gl(NCLS, BATCH, 3);
    k_loss<<<gl, 256, 0, stream>>>(pos0, Sall, D0f, counts, (float*)d_out);
}

// Round 7
// 128.007 us; speedup vs baseline: 1.0460x; 1.0460x over previous
//
#include <hip/hip_runtime.h>
#include <stdint.h>

// Problem constants (from reference)
#define NCLS 19
#define PDIM 128
#define QLEN 2975
#define BATCH 8
#define HW 16384          // 128*128
#define ROWS 152          // BATCH*NCLS key rows per projector
#define ROWS_PAD 160      // padded to 10 MFMA M-tiles
#define NSUB 4            // 128-pixel sub-chunks per k_msum block (512 h)

typedef __attribute__((ext_vector_type(8))) short short8;   // 8 bf16 (4 VGPR)
typedef __attribute__((ext_vector_type(4))) float floatx4;  // MFMA accum

__device__ __forceinline__ uint16_t f2b(float f) {
    uint32_t u = __float_as_uint(f);
    uint32_t r = (u + 0x7FFFu + ((u >> 16) & 1u)) >> 16;   // RNE
    return (uint16_t)r;
}

// ---------------------------------------------------------------------------
// K1: pred = argmax_c logits  (first-max semantics) + per-image class counts
// ---------------------------------------------------------------------------
__global__ __launch_bounds__(256)
void k_pred(const float* __restrict__ logits, uint8_t* __restrict__ pred,
            int* __restrict__ counts) {
    __shared__ int cnt[NCLS];
    int tid = threadIdx.x;
    if (tid < NCLS) cnt[tid] = 0;
    __syncthreads();
    int idx = blockIdx.x * 256 + tid;       // block spans one b (HW % 256 == 0)
    int b = idx >> 14, h = idx & (HW - 1);
    const float* base = logits + (size_t)b * NCLS * HW + h;
    float best = base[0];
    int bi = 0;
#pragma unroll
    for (int c = 1; c < NCLS; ++c) {
        float v = base[(size_t)c * HW];
        if (v > best) { best = v; bi = c; }
    }
    pred[idx] = (uint8_t)bi;
    atomicAdd(&cnt[bi], 1);
    __syncthreads();
    if (tid < NCLS) atomicAdd(&counts[b * NCLS + tid], cnt[tid]);
}

// ---------------------------------------------------------------------------
// K2: masked per-class sums as a one-hot MFMA GEMM.
// Round-7 rewrite: CONTIGUOUS wave-level streaming.  Previous rounds loaded
// B-frags lane-direct, so each instruction's 64 addresses were congruent
// mod 64 KB (d-major rows) -> all segments hit the same L2 channel slice ->
// ~1.3 TB/s ceiling regardless of MLP depth.  Now each wave reads its 16
// d-rows as 8x contiguous-1KB float4 instructions per 128-pixel sub-chunk,
// redistributes through a private 4 KB XOR-swizzled LDS tile (2-way banks on
// both sides, DS ops wave-in-order => no barrier), and prefetches the next
// sub-chunk's loads before consuming the current (static double reg buffer).
// ---------------------------------------------------------------------------
__global__ __launch_bounds__(512, 2)
void k_msum(const float* __restrict__ p0, const float* __restrict__ p1,
            const float* __restrict__ p2, const uint8_t* __restrict__ pred,
            float* __restrict__ sums) {
    __shared__ short lds[8][16][128];        // per-wave [16 d][128 h] bf16 tile
    int chunk = blockIdx.x, b = blockIdx.y, pi = blockIdx.z;
    const float* proj = (pi == 0) ? p0 : (pi == 1) ? p1 : p2;
    int tid = threadIdx.x;
    int wave = tid >> 6, lane = tid & 63;
    int col = lane & 15, g = lane >> 4;      // MFMA lane decomposition
    int lo = lane & 31, hi = lane >> 5;      // load lane decomposition
    int d0 = wave * 16;
    int h0 = chunk * (128 * NSUB);

    const float* fbase = proj + ((size_t)b * PDIM + d0) * HW + h0;
    const uint8_t* pr = pred + (size_t)b * HW + h0;
    char* wlds = (char*)&lds[wave][0][0];

    uint4 fa[2][8];                          // 2 x 8 KB fea staging
    uint64_t fp[2][4];                       // 2 x pred bytes
#pragma unroll
    for (int i = 0; i < 8; ++i)
        fa[0][i] = *(const uint4*)(fbase + (size_t)(i * 2 + hi) * HW + lo * 4);
#pragma unroll
    for (int s = 0; s < 4; ++s)
        fp[0][s] = *(const uint64_t*)(pr + s * 32 + g * 8);

    floatx4 acc0 = (floatx4)(0.f);           // classes 0..15
    floatx4 acc1 = (floatx4)(0.f);           // classes 16..31 (19..31 dead)

#pragma unroll
    for (int sub = 0; sub < NSUB; ++sub) {
        int cur = sub & 1, nxt = cur ^ 1;
        if (sub + 1 < NSUB) {                // prefetch next sub-chunk
            const float* fb = fbase + (sub + 1) * 128;
            const uint8_t* pn = pr + (sub + 1) * 128;
#pragma unroll
            for (int i = 0; i < 8; ++i)
                fa[nxt][i] = *(const uint4*)(fb + (size_t)(i * 2 + hi) * HW + lo * 4);
#pragma unroll
            for (int s = 0; s < 4; ++s)
                fp[nxt][s] = *(const uint64_t*)(pn + s * 32 + g * 8);
        }
        __builtin_amdgcn_sched_barrier(0);   // pin prefetch cluster first

        // pack cur -> bf16, scatter into the wave's LDS tile (swizzled)
#pragma unroll
        for (int i = 0; i < 8; ++i) {
            int r = i * 2 + hi;
            uint2 w;
            w.x = __builtin_amdgcn_perm(fa[cur][i].y, fa[cur][i].x, 0x07060302u);
            w.y = __builtin_amdgcn_perm(fa[cur][i].w, fa[cur][i].z, 0x07060302u);
            int byte = (r * 256 + lo * 8) ^ ((r & 7) << 4);
            *(uint2*)(wlds + byte) = w;
        }

        // 4 K-steps of 32 pixels: B-frag from LDS, one-hot A from pred bytes
#pragma unroll
        for (int s = 0; s < 4; ++s) {
            int byte = (col * 256 + s * 64 + g * 16) ^ ((col & 7) << 4);
            short8 bf = *(const short8*)(wlds + byte);
            union { short8 s8; uint16_t h[8]; } a0, a1;
#pragma unroll
            for (int j = 0; j < 8; ++j) {
                int cb = (int)((fp[cur][s] >> (8 * j)) & 0xFF);
                a0.h[j] = (cb == col)      ? (uint16_t)0x3F80 : (uint16_t)0;
                a1.h[j] = (cb == col + 16) ? (uint16_t)0x3F80 : (uint16_t)0;
            }
            acc0 = __builtin_amdgcn_mfma_f32_16x16x32_bf16(a0.s8, bf, acc0, 0, 0, 0);
            acc1 = __builtin_amdgcn_mfma_f32_16x16x32_bf16(a1.s8, bf, acc1, 0, 0, 0);
        }
    }

    // C/D layout: col = lane&15 (this lane's d), row = 4*(lane>>4) + r
    float* sb = sums + (((size_t)pi * BATCH + b) * NCLS) * PDIM + d0 + col;
#pragma unroll
    for (int r = 0; r < 4; ++r) {
        int row0 = g * 4 + r;                          // 0..15, always valid
        atomicAdd(&sb[(size_t)row0 * PDIM], acc0[r]);
        int row1 = 16 + g * 4 + r;                     // 16..31, valid <19
        if (row1 < NCLS) atomicAdd(&sb[(size_t)row1 * PDIM], acc1[r]);
    }
}

// ---------------------------------------------------------------------------
// K3: keys = normalize(sums / max(count,1)); store bf16 (padded rows stay 0)
// ---------------------------------------------------------------------------
__global__ __launch_bounds__(64)
void k_keys(const float* __restrict__ sums, const int* __restrict__ counts,
            uint16_t* __restrict__ keysb) {
    int c = blockIdx.x, b = blockIdx.y, pi = blockIdx.z;
    int lane = threadIdx.x;
    size_t base = (((size_t)pi * BATCH + b) * NCLS + c) * PDIM;
    int cn = counts[b * NCLS + c];
    float cnt = (float)(cn > 0 ? cn : 1);
    float m0 = sums[base + lane] / cnt;
    float m1 = sums[base + lane + 64] / cnt;
    float nr = m0 * m0 + m1 * m1;
    for (int off = 32; off; off >>= 1) nr += __shfl_xor(nr, off);
    float scale = 1.f / fmaxf(sqrtf(nr), 1e-12f);
    size_t bb = ((size_t)pi * ROWS_PAD + b * NCLS + c) * PDIM;
    keysb[bb + lane]      = f2b(m0 * scale);
    keysb[bb + lane + 64] = f2b(m1 * scale);
}

// ---------------------------------------------------------------------------
// K4: sim matmul + exp-sum.  Deep-MLP version: ALL 64 queue dword loads for
// both l-strips are issued as one independent batch (one latency exposure per
// block) before any packing/MFMA.  __launch_bounds__(256,2) lifts the VGPR
// ceiling so the staging registers can all live at once.
// Keys LDS: [kgrp][row^(kgrp&7)] short8 slots, 2-way-free banks, 40960 B.
// Queue-enqueue feedback dropped (~1e-3 effect vs threshold 12.4).
// ---------------------------------------------------------------------------
__global__ __launch_bounds__(256, 2)
void k_sim(const float* __restrict__ q, const uint16_t* __restrict__ keysb,
           float* __restrict__ Sall, float* __restrict__ D0,
           float* __restrict__ pos0) {
    __shared__ char smem[40960];                // keys panel, then rowsum
    int tile = blockIdx.x, k = blockIdx.y, pi = blockIdx.z;
    int tid = threadIdx.x;
    int wave = tid >> 6, lane = tid & 63;
    int col = lane & 15, g = lane >> 4;

    { // stage keys: global row-major -> LDS kgrp-major, XOR-swizzled rows
        const uint4* kg = (const uint4*)(keysb + (size_t)pi * ROWS_PAD * PDIM);
        uint4* kl = (uint4*)smem;
        int kgrp = tid & 15;
        int r0 = tid >> 4;
#pragma unroll
        for (int it = 0; it < 10; ++it) {
            int row = r0 + it * 16;
            kl[kgrp * 160 + (row ^ (kgrp & 7))] = kg[row * 16 + kgrp];
        }
    }

    int l0 = tile * 128 + wave * 16 + col;      // strip A col
    int l1 = l0 + 64;                           // strip B col
    bool okA = l0 < QLEN, okB = l1 < QLEN;
    const uint32_t* qbase = (const uint32_t*)(q + ((size_t)pi * NCLS + k) * (size_t)PDIM * QLEN);
    const uint32_t* qA = qbase + (okA ? l0 : (QLEN - 1));
    const uint32_t* qB = qbase + (okB ? l1 : (QLEN - 1));

    // ---- batch-issue all 64 independent queue loads -----------------------
    uint32_t uA[32], uB[32];
#pragma unroll
    for (int s = 0; s < 4; ++s) {
#pragma unroll
        for (int j = 0; j < 8; ++j) {
            size_t off = (size_t)(s * 32 + g * 8 + j) * QLEN;
            uA[s * 8 + j] = qA[off];
            uB[s * 8 + j] = qB[off];
        }
    }

    __syncthreads();                            // keys visible (drains loads too)

    // ---- pack to bf16 ------------------------------------------------------
    uint32_t wA[16], wB[16];
#pragma unroll
    for (int t = 0; t < 16; ++t) {
        wA[t] = __builtin_amdgcn_perm(uA[2 * t + 1], uA[2 * t], 0x07060302u);
        wB[t] = __builtin_amdgcn_perm(uB[2 * t + 1], uB[2 * t], 0x07060302u);
    }

    // ---- MFMA: 10 M-tiles x 4 K-steps x 2 strips ---------------------------
    floatx4 accA[10], accB[10];
#pragma unroll
    for (int m = 0; m < 10; ++m) { accA[m] = (floatx4)(0.f); accB[m] = (floatx4)(0.f); }

    const short8* kls = (const short8*)smem;
#pragma unroll
    for (int s = 0; s < 4; ++s) {
        union { short8 s8; uint32_t w[4]; } bfA, bfB;
#pragma unroll
        for (int i = 0; i < 4; ++i) { bfA.w[i] = wA[s * 4 + i]; bfB.w[i] = wB[s * 4 + i]; }
        int kgrp = s * 4 + g;
        int kxor = kgrp & 7;
        const short8* kp = kls + (size_t)kgrp * 160;
#pragma unroll
        for (int m = 0; m < 10; ++m) {
            short8 af = kp[(m * 16 + col) ^ kxor];
            accA[m] = __builtin_amdgcn_mfma_f32_16x16x32_bf16(af, bfA.s8, accA[m], 0, 0, 0);
            accB[m] = __builtin_amdgcn_mfma_f32_16x16x32_bf16(af, bfB.s8, accB[m], 0, 0, 0);
        }
    }

    __syncthreads();                            // all keys reads complete
    float* rowsum = (float*)smem;               // alias keys panel
    if (tid < ROWS_PAD) rowsum[tid] = 0.f;
    __syncthreads();

    const float inv = 1.f / (float)PDIM;
#pragma unroll
    for (int m = 0; m < 10; ++m) {
#pragma unroll
        for (int r = 0; r < 4; ++r) {
            int row = m * 16 + g * 4 + r;       // C/D: col=lane&15, row=4*g+r
            bool rok = row < ROWS;
            float sA = accA[m][r] * inv;
            float sB = accB[m][r] * inv;
            float e = 0.f;
            if (rok) e = (okA ? __expf(sA) : 0.f) + (okB ? __expf(sB) : 0.f);
#pragma unroll
            for (int off = 1; off < 16; off <<= 1) e += __shfl_xor(e, off);
            if (col == 0 && rok) atomicAdd(&rowsum[row], e);
            if (rok) {
                int bb = row / NCLS, cc = row - bb * NCLS;
                if (cc == k) {
                    float* pb = pos0 + (((size_t)pi * BATCH + bb) * NCLS + cc) * QLEN;
                    if (okA) pb[l0] = sA;
                    if (okB) pb[l1] = sB;
                }
            }
        }
    }
    __syncthreads();
    if (tid < ROWS) {
        float v = rowsum[tid];
        atomicAdd(&Sall[pi * ROWS + tid], v);
        int cc = tid % NCLS;
        if (cc == k) atomicAdd(&D0[pi * ROWS + tid], v);
    }
}

// ---------------------------------------------------------------------------
// K5: loss; one block per (c, b, pi).
// ---------------------------------------------------------------------------
__global__ __launch_bounds__(256)
void k_loss(const float* __restrict__ pos0, const float* __restrict__ Sall,
            const float* __restrict__ D0, const int* __restrict__ counts,
            float* __restrict__ out) {
    int c = blockIdx.x, b = blockIdx.y, pi = blockIdx.z;
    if (counts[b * NCLS + c] <= 0) return;      // block-uniform
    int tid = threadIdx.x;
    int row = b * NCLS + c;
    float sneg = Sall[pi * ROWS + row] - D0[pi * ROWS + row];
    const float* pp = pos0 + (((size_t)pi * BATCH + b) * NCLS + c) * QLEN;
    float sum = 0.f;
    for (int l = tid; l < QLEN; l += 256) {
        float p = pp[l];
        sum += p - logf(__expf(p) + sneg);
    }
    __shared__ float red[4];
    int wave = tid >> 6, lane = tid & 63;
    for (int off = 32; off; off >>= 1) sum += __shfl_down(sum, off);
    if (lane == 0) red[wave] = sum;
    __syncthreads();
    if (tid == 0) {
        float t = red[0] + red[1] + red[2] + red[3];
        atomicAdd(out, -t / ((float)QLEN * (float)BATCH));
    }
}

// ---------------------------------------------------------------------------
extern "C" void kernel_launch(void* const* d_in, const int* in_sizes, int n_in,
                              void* d_out, int out_size, void* d_ws, size_t ws_size,
                              hipStream_t stream) {
    const float* proj3  = (const float*)d_in[0];
    const float* proj4  = (const float*)d_in[1];
    const float* proj5  = (const float*)d_in[2];
    const float* logits = (const float*)d_in[3];
    const float* queues = (const float*)d_in[4];

    // workspace layout (~5.9 MB total)
    char* ws = (char*)d_ws;
    int*      counts = (int*)ws;                          // 608 B  (pad 1024)
    uint8_t*  pred   = (uint8_t*)(ws + 1024);             // 131072 B
    float*    sums   = (float*)(ws + 1024 + 131072);      // 233472 B
    uint16_t* keysb  = (uint16_t*)(ws + 365568);          // 122880 B (3*160*128 bf16)
    float*    Sall   = (float*)(ws + 488448);             // 1824 B (pad 2048)
    float*    D0f    = (float*)(ws + 490496);             // 1824 B (pad 2048)
    float*    pos0   = (float*)(ws + 492544);             // 5426400 B

    // zero accumulators + keysb padding rows; must happen EVERY launch
    hipMemsetAsync(ws, 0, 492544, stream);
    hipMemsetAsync(d_out, 0, sizeof(float), stream);

    k_pred<<<dim3(512), 256, 0, stream>>>(logits, pred, counts);

    dim3 gs(HW / (128 * NSUB), BATCH, 3);            // 32 x 8 x 3
    k_msum<<<gs, 512, 0, stream>>>(proj3, proj4, proj5, pred, sums);

    dim3 gk(NCLS, BATCH, 3);
    k_keys<<<gk, 64, 0, stream>>>(sums, counts, keysb);

    dim3 gm((QLEN + 127) / 128, NCLS, 3);            // 24 x 19 x 3
    k_sim<<<gm, 256, 0, stream>>>(queues, keysb, Sall, D0f, pos0);

    dim3 gl(NCLS, BATCH, 3);
    k_loss<<<gl, 256, 0, stream>>>(pos0, Sall, D0f, counts, (float*)d_out);
}